// Round 2
// baseline (285.272 us; speedup 1.0000x reference)
//
#include <hip/hip_runtime.h>

#define NPTS_KPC   200000
#define KKP        9
#define CIN        64
#define COUT       64
#define KPE_INV    (1.0f / 0.15f)

struct Entry {
    int   n;        // point index
    int   m;        // segment index
    float w[KKP];   // 9 kernel weights
};                  // 44 bytes

// Kernel 1: find active points (any nonzero kernel weight), compact into list.
__global__ void kpconv_scan(const float* __restrict__ s_pts,
                            const int*   __restrict__ unq_inv,
                            const float* __restrict__ kpts,   // [9][3]
                            int*         __restrict__ counter,
                            Entry*       __restrict__ list,
                            int capacity, int n)
{
    int i = blockIdx.x * blockDim.x + threadIdx.x;
    if (i >= n) return;

    float px = s_pts[3 * i + 0];
    float py = s_pts[3 * i + 1];
    float pz = s_pts[3 * i + 2];

    // All kernel points have |kp| <= 0.0375. If |p| > 0.19 then for every k:
    // |p - kp| >= 0.19 - 0.0375 = 0.1525 > 0.15  =>  every weight clips to 0.
    float r2 = px * px + py * py + pz * pz;
    if (r2 > 0.0361f) return;   // 0.19^2

    float w[KKP];
    float wmax = 0.0f;
    #pragma unroll
    for (int k = 0; k < KKP; ++k) {
        float dx = px - kpts[3 * k + 0];
        float dy = py - kpts[3 * k + 1];
        float dz = pz - kpts[3 * k + 2];
        float d  = sqrtf(dx * dx + dy * dy + dz * dz);
        float wk = 1.0f - d * KPE_INV;
        wk = wk > 0.0f ? wk : 0.0f;
        w[k] = wk;
        wmax = fmaxf(wmax, wk);
    }
    if (wmax <= 0.0f) return;

    int idx = atomicAdd(counter, 1);
    if (idx >= capacity) return;

    Entry e;
    e.n = i;
    e.m = unq_inv[i];
    #pragma unroll
    for (int k = 0; k < KKP; ++k) e.w[k] = w[k];
    list[idx] = e;
}

// Kernel 2: for each active entry, out[m, o] += sum_k w[k] * sum_c x[n,c]*W[k,c,o]
// One 64-thread block per entry (block-stride over runtime count); thread = o.
__global__ void kpconv_apply(const float* __restrict__ x,
                             const float* __restrict__ weights, // [9][64][64]
                             const int*   __restrict__ counter,
                             const Entry* __restrict__ list,
                             int capacity,
                             float*       __restrict__ out)
{
    __shared__ float xs[CIN];
    int cnt = *counter;
    if (cnt > capacity) cnt = capacity;
    int o = threadIdx.x;

    for (int idx = blockIdx.x; idx < cnt; idx += gridDim.x) {
        Entry e = list[idx];
        __syncthreads();                 // protect xs across loop iterations
        xs[o] = x[(size_t)e.n * CIN + o];
        __syncthreads();

        float acc = 0.0f;
        #pragma unroll
        for (int k = 0; k < KKP; ++k) {
            float wk = e.w[k];           // uniform across block -> no divergence
            if (wk == 0.0f) continue;
            const float* Wk = weights + (size_t)k * CIN * COUT + o;
            float a = 0.0f;
            #pragma unroll
            for (int c = 0; c < CIN; ++c)
                a += xs[c] * Wk[(size_t)c * COUT];  // coalesced over o
            acc += wk * a;
        }
        atomicAdd(&out[(size_t)e.m * COUT + o], acc);
    }
}

extern "C" void kernel_launch(void* const* d_in, const int* in_sizes, int n_in,
                              void* d_out, int out_size, void* d_ws, size_t ws_size,
                              hipStream_t stream)
{
    const float* s_pts   = (const float*)d_in[0];
    const float* x       = (const float*)d_in[1];
    const int*   unq_inv = (const int*)  d_in[2];
    const float* weights = (const float*)d_in[3];
    const float* kpts    = (const float*)d_in[4];
    float*       out     = (float*)d_out;

    int n = in_sizes[0] / 3;                    // 200000 points

    int*   counter = (int*)d_ws;
    Entry* list    = (Entry*)((char*)d_ws + 128);
    long long cap_ll = ((long long)ws_size - 128) / (long long)sizeof(Entry);
    int capacity = (cap_ll > n) ? n : (cap_ll < 0 ? 0 : (int)cap_ll);

    hipMemsetAsync(d_ws, 0, 8, stream);                                   // counter = 0
    hipMemsetAsync(d_out, 0, (size_t)out_size * sizeof(float), stream);   // out = 0

    kpconv_scan<<<(n + 255) / 256, 256, 0, stream>>>(
        s_pts, unq_inv, kpts, counter, list, capacity, n);

    kpconv_apply<<<1024, 64, 0, stream>>>(
        x, weights, counter, list, capacity, out);
}